// Round 2
// baseline (400.103 us; speedup 1.0000x reference)
//
#include <hip/hip_runtime.h>
#include <math.h>

#define CHUNKS 4      // gt chunks for k1 parallelism (M/CHUNKS must be <= 1024)
#define NCH 64        // feat row-chunks for k3

// ---------------- k1: pairwise IoU partial max+argmax over a gt chunk ----------------
// Uses correctly-rounded fp32 division so each iou is bitwise equal to numpy;
// strict '>' keeps the first index, matching jnp.argmax.
__global__ __launch_bounds__(256) void k_pairwise(
    const float* __restrict__ rois, const float* __restrict__ gt,
    unsigned long long* __restrict__ partials, int N, int M) {
  const int mper = M / CHUNKS;            // 1024
  const int j0 = blockIdx.y * mper;
  __shared__ float4 sg[1024];
  __shared__ float  sa[1024];
  for (int j = threadIdx.x; j < mper; j += blockDim.x) {
    float4 g = ((const float4*)gt)[j0 + j];
    sg[j] = g;
    sa[j] = (g.z - g.x) * (g.w - g.y);
  }
  __syncthreads();

  const int i = blockIdx.x * blockDim.x + threadIdx.x;
  float4 r = ((const float4*)rois)[i];
  float area_a = (r.z - r.x) * (r.w - r.y);

  float biou = -1.f;
  int bj = 0;
  for (int j = 0; j < mper; ++j) {
    float4 g = sg[j];
    float ix = fminf(r.z, g.z) - fmaxf(r.x, g.x);
    float iy = fminf(r.w, g.w) - fmaxf(r.y, g.y);
    ix = fmaxf(ix, 0.f);
    iy = fmaxf(iy, 0.f);
    float inter = ix * iy;
    float uni = area_a + sa[j] - inter;
    float iou = inter / uni;             // correctly-rounded: bitwise == numpy
    bool win = iou > biou;               // strict > keeps first (smallest j)
    biou = win ? iou : biou;
    bj = win ? j : bj;
  }
  unsigned int idx = (unsigned int)(j0 + bj);
  // sortable key: higher iou wins; equal iou -> smaller idx wins (first occurrence)
  unsigned long long key =
      ((unsigned long long)__float_as_uint(biou) << 32) |
      (unsigned long long)(0xFFFFFFFFu - idx);
  partials[(size_t)blockIdx.y * N + i] = key;
}

// ---------------- k2: per-roi finalize: mask, refine, loss, masked outputs ----------------
__global__ __launch_bounds__(256) void k_finalize(
    const float* __restrict__ rois, const float* __restrict__ deltas,
    const float* __restrict__ gt, const unsigned long long* __restrict__ partials,
    float* __restrict__ mask, int* __restrict__ counter,
    float* __restrict__ out_loss, float* __restrict__ out_refined, int N) {
  const int i = blockIdx.x * blockDim.x + threadIdx.x;
  unsigned long long best = 0ull;
  for (int c = 0; c < CHUNKS; ++c) {
    unsigned long long k = partials[(size_t)c * N + i];
    best = (k > best) ? k : best;
  }
  float iou = __uint_as_float((unsigned int)(best >> 32));
  int idx = (int)(0xFFFFFFFFu - (unsigned int)(best & 0xFFFFFFFFull));
  float m = (iou > 0.5f) ? 1.f : 0.f;
  mask[i] = m;
  if (m != 0.f) atomicAdd(counter, 1);

  float4 r = ((const float4*)rois)[i];
  float4 d = ((const float4*)deltas)[i];
  float w = r.z - r.x + 1.f, h = r.w - r.y + 1.f;
  float cx = r.x + 0.5f * w, cy = r.y + 0.5f * h;
  float pcx = d.x * w + cx, pcy = d.y * h + cy;
  float pw = expf(d.z) * w, ph = expf(d.w) * h;
  float rx0 = pcx - 0.5f * pw, ry0 = pcy - 0.5f * ph;
  float rx1 = pcx + 0.5f * pw, ry1 = pcy + 0.5f * ph;

  float4 g = ((const float4*)gt)[idx];
  float ix = fminf(rx1, g.z) - fmaxf(rx0, g.x);
  float iy = fminf(ry1, g.w) - fmaxf(ry0, g.y);
  ix = fmaxf(ix, 0.f);
  iy = fmaxf(iy, 0.f);
  float inter = ix * iy;
  float aa = (rx1 - rx0) * (ry1 - ry0);
  float ab = (g.z - g.x) * (g.w - g.y);
  float er = inter / (aa + ab - inter);

  out_loss[i] = -logf(er + 0.1f) * m;
  out_refined[4 * i + 0] = rx0 * m;
  out_refined[4 * i + 1] = ry0 * m;
  out_refined[4 * i + 2] = rx1 * m;
  out_refined[4 * i + 3] = ry1 * m;
}

// ---------------- k3: mask-weighted partial column sums of feat ----------------
__global__ __launch_bounds__(256) void k_featpartial(
    const float* __restrict__ feat, const float* __restrict__ mask,
    float* __restrict__ pcols, int N, int D) {
  const int d = blockIdx.x * blockDim.x + threadIdx.x;   // column
  const int rows = N / NCH;
  const int n0 = blockIdx.y * rows;
  float acc = 0.f;
  for (int n = n0; n < n0 + rows; ++n) {
    float mv = mask[n];                  // block-uniform -> scalar branch
    if (mv != 0.f) acc += feat[(size_t)n * D + d] * mv;
  }
  pcols[(size_t)blockIdx.y * D + d] = acc;
}

// ---------------- k4: feat_loss reduce + scalar outputs ----------------
__global__ __launch_bounds__(512) void k_final(
    const float* __restrict__ pcols, const int* __restrict__ counter,
    float* __restrict__ out, int N, int D) {
  float acc = 0.f;
  for (int dd = threadIdx.x; dd < D; dd += blockDim.x) {
    float s = 0.f;
    for (int c = 0; c < NCH; ++c) s += pcols[c * D + dd];
    acc += fabsf(s);
  }
  __shared__ float red[8];
  for (int off = 32; off > 0; off >>= 1) acc += __shfl_down(acc, off, 64);
  int wid = threadIdx.x >> 6;
  if ((threadIdx.x & 63) == 0) red[wid] = acc;
  __syncthreads();
  if (threadIdx.x == 0) {
    float t = 0.f;
    int nw = blockDim.x >> 6;
    for (int w = 0; w < nw; ++w) t += red[w];
    out[N] = (float)(*counter);          // n_matched
    out[N + 1] = (float)N;               // num_rois
    out[(size_t)5 * N + 2] = t;          // feat_loss
  }
}

extern "C" void kernel_launch(void* const* d_in, const int* in_sizes, int n_in,
                              void* d_out, int out_size, void* d_ws, size_t ws_size,
                              hipStream_t stream) {
  const float* rois = (const float*)d_in[0];
  const float* bbox = (const float*)d_in[1];
  const float* gt   = (const float*)d_in[2];
  const float* feat = (const float*)d_in[3];
  const int N = in_sizes[0] / 4;   // 32768
  const int M = in_sizes[2] / 4;   // 4096
  const int D = in_sizes[3] / N;   // 512
  float* out = (float*)d_out;

  char* ws = (char*)d_ws;
  unsigned long long* partials = (unsigned long long*)ws;
  size_t off = (size_t)CHUNKS * N * sizeof(unsigned long long);
  float* mask = (float*)(ws + off);  off += (size_t)N * sizeof(float);
  float* pcols = (float*)(ws + off); off += (size_t)NCH * D * sizeof(float);
  int* counter = (int*)(ws + off);

  hipMemsetAsync(counter, 0, sizeof(int), stream);

  dim3 g1(N / 256, CHUNKS);
  k_pairwise<<<g1, 256, 0, stream>>>(rois, gt, partials, N, M);
  k_finalize<<<N / 256, 256, 0, stream>>>(rois, bbox, gt, partials, mask, counter,
                                          out, out + N + 2, N);
  dim3 g3(D / 256, NCH);
  k_featpartial<<<g3, 256, 0, stream>>>(feat, mask, pcols, N, D);
  k_final<<<1, 512, 0, stream>>>(pcols, counter, out, N, D);
}

// Round 3
// 247.549 us; speedup vs baseline: 1.6163x; 1.6163x over previous
//
#include <hip/hip_runtime.h>
#include <math.h>

#define CHUNKS 4      // gt chunks for k1 parallelism (M/CHUNKS must be <= 1024)
#define K3B 512       // blocks for k_feat (N/K3B rows per block)
#define K3R 64        // rows per k_feat block = N/K3B

// ---------------- k1: pairwise IoU partial max+argmax over a gt chunk ----------------
// Correctly-rounded fp32 division -> each iou bitwise == numpy; strict '>' keeps
// first index (jnp.argmax semantics).
__global__ __launch_bounds__(256) void k_pairwise(
    const float* __restrict__ rois, const float* __restrict__ gt,
    unsigned long long* __restrict__ partials, int N, int M) {
  const int mper = M / CHUNKS;            // 1024
  const int j0 = blockIdx.y * mper;
  __shared__ float4 sg[1024];
  __shared__ float  sa[1024];
  for (int j = threadIdx.x; j < mper; j += blockDim.x) {
    float4 g = ((const float4*)gt)[j0 + j];
    sg[j] = g;
    sa[j] = (g.z - g.x) * (g.w - g.y);
  }
  __syncthreads();

  const int i = blockIdx.x * blockDim.x + threadIdx.x;
  float4 r = ((const float4*)rois)[i];
  float area_a = (r.z - r.x) * (r.w - r.y);

  float biou = -1.f;
  int bj = 0;
  for (int j = 0; j < mper; ++j) {
    float4 g = sg[j];
    float ix = fminf(r.z, g.z) - fmaxf(r.x, g.x);
    float iy = fminf(r.w, g.w) - fmaxf(r.y, g.y);
    ix = fmaxf(ix, 0.f);
    iy = fmaxf(iy, 0.f);
    float inter = ix * iy;
    float uni = area_a + sa[j] - inter;
    float iou = inter / uni;             // correctly-rounded: bitwise == numpy
    bool win = iou > biou;               // strict > keeps first (smallest j)
    biou = win ? iou : biou;
    bj = win ? j : bj;
  }
  unsigned int idx = (unsigned int)(j0 + bj);
  unsigned long long key =
      ((unsigned long long)__float_as_uint(biou) << 32) |
      (unsigned long long)(0xFFFFFFFFu - idx);
  partials[(size_t)blockIdx.y * N + i] = key;
}

// ---------------- k2: per-roi finalize: mask, refine, loss, masked outputs ----------------
__global__ __launch_bounds__(256) void k_finalize(
    const float* __restrict__ rois, const float* __restrict__ deltas,
    const float* __restrict__ gt, const unsigned long long* __restrict__ partials,
    float* __restrict__ mask, int* __restrict__ counter,
    float* __restrict__ out_loss, float* __restrict__ out_refined, int N) {
  const int i = blockIdx.x * blockDim.x + threadIdx.x;
  unsigned long long best = 0ull;
  for (int c = 0; c < CHUNKS; ++c) {
    unsigned long long k = partials[(size_t)c * N + i];
    best = (k > best) ? k : best;
  }
  float iou = __uint_as_float((unsigned int)(best >> 32));
  int idx = (int)(0xFFFFFFFFu - (unsigned int)(best & 0xFFFFFFFFull));
  float m = (iou > 0.5f) ? 1.f : 0.f;
  mask[i] = m;
  if (m != 0.f) atomicAdd(counter, 1);

  float4 r = ((const float4*)rois)[i];
  float4 d = ((const float4*)deltas)[i];
  float w = r.z - r.x + 1.f, h = r.w - r.y + 1.f;
  float cx = r.x + 0.5f * w, cy = r.y + 0.5f * h;
  float pcx = d.x * w + cx, pcy = d.y * h + cy;
  float pw = expf(d.z) * w, ph = expf(d.w) * h;
  float rx0 = pcx - 0.5f * pw, ry0 = pcy - 0.5f * ph;
  float rx1 = pcx + 0.5f * pw, ry1 = pcy + 0.5f * ph;

  float4 g = ((const float4*)gt)[idx];
  float ix = fminf(rx1, g.z) - fmaxf(rx0, g.x);
  float iy = fminf(ry1, g.w) - fmaxf(ry0, g.y);
  ix = fmaxf(ix, 0.f);
  iy = fmaxf(iy, 0.f);
  float inter = ix * iy;
  float aa = (rx1 - rx0) * (ry1 - ry0);
  float ab = (g.z - g.x) * (g.w - g.y);
  float er = inter / (aa + ab - inter);

  out_loss[i] = -logf(er + 0.1f) * m;
  out_refined[4 * i + 0] = rx0 * m;
  out_refined[4 * i + 1] = ry0 * m;
  out_refined[4 * i + 2] = rx1 * m;
  out_refined[4 * i + 3] = ry1 * m;
}

// ---------------- k3: row-parallel mask-weighted column sums of feat ----------------
// Block owns K3R rows; each iteration reads 2 full rows coalesced (128 float4
// lanes per row). Wave-uniform mask test skips unmatched rows entirely.
__global__ __launch_bounds__(256) void k_feat(
    const float4* __restrict__ feat4, const float* __restrict__ mask,
    float4* __restrict__ pcols4, int N, int D4) {
  const int n0 = blockIdx.x * K3R;
  const int c = threadIdx.x & 127;       // float4 column
  const int p = threadIdx.x >> 7;        // row parity
  float4 acc = {0.f, 0.f, 0.f, 0.f};
  for (int it = 0; it < K3R; it += 2) {
    int n = n0 + it + p;
    float mv = mask[n];                  // uniform per half-block -> uniform branch
    if (mv != 0.f) {
      float4 v = feat4[(size_t)n * D4 + c];
      acc.x += v.x; acc.y += v.y; acc.z += v.z; acc.w += v.w;
    }
  }
  __shared__ float4 red[256];
  red[threadIdx.x] = acc;
  __syncthreads();
  if (threadIdx.x < 128) {
    float4 o = red[threadIdx.x + 128];
    acc = red[threadIdx.x];
    acc.x += o.x; acc.y += o.y; acc.z += o.z; acc.w += o.w;
    pcols4[(size_t)blockIdx.x * D4 + threadIdx.x] = acc;
  }
}

// ---------------- k4a: reduce K3B partial rows -> 64 ----------------
__global__ __launch_bounds__(256) void k_red1(
    const float4* __restrict__ pcols4, float4* __restrict__ pcols2, int D4) {
  const int c = threadIdx.x & 127;
  const int h = threadIdx.x >> 7;
  const int per = K3B / 64;              // 8 partial rows per block
  float4 acc = {0.f, 0.f, 0.f, 0.f};
  for (int r = 0; r < per / 2; ++r) {
    float4 v = pcols4[(size_t)(blockIdx.x * per + h * (per / 2) + r) * D4 + c];
    acc.x += v.x; acc.y += v.y; acc.z += v.z; acc.w += v.w;
  }
  __shared__ float4 red[256];
  red[threadIdx.x] = acc;
  __syncthreads();
  if (threadIdx.x < 128) {
    float4 o = red[threadIdx.x + 128];
    acc = red[threadIdx.x];
    acc.x += o.x; acc.y += o.y; acc.z += o.z; acc.w += o.w;
    pcols2[(size_t)blockIdx.x * D4 + threadIdx.x] = acc;
  }
}

// ---------------- k4b: feat_loss reduce + scalar outputs ----------------
__global__ __launch_bounds__(512) void k_final(
    const float* __restrict__ pcols2, const int* __restrict__ counter,
    float* __restrict__ out, int N, int D) {
  float acc = 0.f;
  for (int dd = threadIdx.x; dd < D; dd += blockDim.x) {
    float s = 0.f;
    for (int c = 0; c < 64; ++c) s += pcols2[c * D + dd];
    acc += fabsf(s);
  }
  __shared__ float red[8];
  for (int off = 32; off > 0; off >>= 1) acc += __shfl_down(acc, off, 64);
  int wid = threadIdx.x >> 6;
  if ((threadIdx.x & 63) == 0) red[wid] = acc;
  __syncthreads();
  if (threadIdx.x == 0) {
    float t = 0.f;
    int nw = blockDim.x >> 6;
    for (int w = 0; w < nw; ++w) t += red[w];
    out[N] = (float)(*counter);          // n_matched
    out[N + 1] = (float)N;               // num_rois
    out[(size_t)5 * N + 2] = t;          // feat_loss
  }
}

extern "C" void kernel_launch(void* const* d_in, const int* in_sizes, int n_in,
                              void* d_out, int out_size, void* d_ws, size_t ws_size,
                              hipStream_t stream) {
  const float* rois = (const float*)d_in[0];
  const float* bbox = (const float*)d_in[1];
  const float* gt   = (const float*)d_in[2];
  const float* feat = (const float*)d_in[3];
  const int N = in_sizes[0] / 4;   // 32768
  const int M = in_sizes[2] / 4;   // 4096
  const int D = in_sizes[3] / N;   // 512
  float* out = (float*)d_out;

  char* ws = (char*)d_ws;
  unsigned long long* partials = (unsigned long long*)ws;
  size_t off = (size_t)CHUNKS * N * sizeof(unsigned long long);
  float* mask = (float*)(ws + off);   off += (size_t)N * sizeof(float);
  float* pcols = (float*)(ws + off);  off += (size_t)K3B * D * sizeof(float);
  float* pcols2 = (float*)(ws + off); off += (size_t)64 * D * sizeof(float);
  int* counter = (int*)(ws + off);

  hipMemsetAsync(counter, 0, sizeof(int), stream);

  dim3 g1(N / 256, CHUNKS);
  k_pairwise<<<g1, 256, 0, stream>>>(rois, gt, partials, N, M);
  k_finalize<<<N / 256, 256, 0, stream>>>(rois, bbox, gt, partials, mask, counter,
                                          out, out + N + 2, N);
  k_feat<<<K3B, 256, 0, stream>>>((const float4*)feat, mask, (float4*)pcols, N, D / 4);
  k_red1<<<64, 256, 0, stream>>>((const float4*)pcols, (float4*)pcols2, D / 4);
  k_final<<<1, 512, 0, stream>>>(pcols2, counter, out, N, D);
}

// Round 4
// 209.851 us; speedup vs baseline: 1.9066x; 1.1796x over previous
//
#include <hip/hip_runtime.h>
#include <math.h>

#define CHUNKS 8      // gt chunks for k1 parallelism
#define K3B 512       // blocks for k_feat
#define K3R 64        // rows per k_feat block = N/K3B

// 1 - 2^-18, exactly representable
#define EPS1 0.999996185302734375f

// ---------------- k1: pairwise IoU partial max+argmax over a gt chunk ----------------
// Hot loop avoids division: conservative prefilter inter > thresh*uni with
// thresh = biou*(1-2^-18). Guarantees every j with round(inter/uni) > biou takes
// the branch; the branch redoes the exact correctly-rounded division and strict
// '>' compare, so the result is bitwise identical to the always-divide loop
// (numpy max/argmax semantics, first-index ties).
__global__ __launch_bounds__(256) void k_pairwise(
    const float* __restrict__ rois, const float* __restrict__ gt,
    unsigned long long* __restrict__ partials, int N, int M) {
  const int mper = M / CHUNKS;            // 512
  const int j0 = blockIdx.y * mper;
  __shared__ float4 sg[512];
  __shared__ float  sa[512];
  for (int j = threadIdx.x; j < mper; j += blockDim.x) {
    float4 g = ((const float4*)gt)[j0 + j];
    sg[j] = g;
    sa[j] = (g.z - g.x) * (g.w - g.y);
  }
  __syncthreads();

  const int i = blockIdx.x * blockDim.x + threadIdx.x;
  float4 r = ((const float4*)rois)[i];
  float area_a = (r.z - r.x) * (r.w - r.y);

  float biou = -1.f;
  float thresh = -1.f;                    // any negative: forces first branch
  int bj = 0;
  for (int j = 0; j < mper; ++j) {
    float4 g = sg[j];                     // wave-uniform -> LDS broadcast
    float ix = fminf(r.z, g.z) - fmaxf(r.x, g.x);
    float iy = fminf(r.w, g.w) - fmaxf(r.y, g.y);
    float inter = fmaxf(ix, 0.f) * fmaxf(iy, 0.f);
    float uni = (area_a + sa[j]) - inter;
    if (inter > thresh * uni) {           // conservative candidate filter
      float iou = inter / uni;            // correctly-rounded: bitwise == numpy
      if (iou > biou) {                   // strict > keeps first (smallest j)
        biou = iou; bj = j;
        thresh = biou * EPS1;
      }
    }
  }
  unsigned int idx = (unsigned int)(j0 + bj);
  unsigned long long key =
      ((unsigned long long)__float_as_uint(biou) << 32) |
      (unsigned long long)(0xFFFFFFFFu - idx);
  partials[(size_t)blockIdx.y * N + i] = key;
}

// ---------------- k2: per-roi finalize: mask, refine, loss, masked outputs ----------------
__global__ __launch_bounds__(256) void k_finalize(
    const float* __restrict__ rois, const float* __restrict__ deltas,
    const float* __restrict__ gt, const unsigned long long* __restrict__ partials,
    float* __restrict__ mask, int* __restrict__ counter,
    float* __restrict__ out_loss, float* __restrict__ out_refined, int N) {
  const int i = blockIdx.x * blockDim.x + threadIdx.x;
  unsigned long long best = 0ull;
  for (int c = 0; c < CHUNKS; ++c) {
    unsigned long long k = partials[(size_t)c * N + i];
    best = (k > best) ? k : best;
  }
  float iou = __uint_as_float((unsigned int)(best >> 32));
  int idx = (int)(0xFFFFFFFFu - (unsigned int)(best & 0xFFFFFFFFull));
  float m = (iou > 0.5f) ? 1.f : 0.f;
  mask[i] = m;
  if (m != 0.f) atomicAdd(counter, 1);

  float4 r = ((const float4*)rois)[i];
  float4 d = ((const float4*)deltas)[i];
  float w = r.z - r.x + 1.f, h = r.w - r.y + 1.f;
  float cx = r.x + 0.5f * w, cy = r.y + 0.5f * h;
  float pcx = d.x * w + cx, pcy = d.y * h + cy;
  float pw = expf(d.z) * w, ph = expf(d.w) * h;
  float rx0 = pcx - 0.5f * pw, ry0 = pcy - 0.5f * ph;
  float rx1 = pcx + 0.5f * pw, ry1 = pcy + 0.5f * ph;

  float4 g = ((const float4*)gt)[idx];
  float ix = fminf(rx1, g.z) - fmaxf(rx0, g.x);
  float iy = fminf(ry1, g.w) - fmaxf(ry0, g.y);
  ix = fmaxf(ix, 0.f);
  iy = fmaxf(iy, 0.f);
  float inter = ix * iy;
  float aa = (rx1 - rx0) * (ry1 - ry0);
  float ab = (g.z - g.x) * (g.w - g.y);
  float er = inter / (aa + ab - inter);

  out_loss[i] = -logf(er + 0.1f) * m;
  out_refined[4 * i + 0] = rx0 * m;
  out_refined[4 * i + 1] = ry0 * m;
  out_refined[4 * i + 2] = rx1 * m;
  out_refined[4 * i + 3] = ry1 * m;
}

// ---------------- k3: row-parallel mask-weighted column sums of feat ----------------
// Masks for the block's 64 rows are gathered once into a ballot bitmask, so the
// row loop has no memory-dependent branches: 2 independent row loads in flight
// per thread, 4 rows per iteration across the two half-blocks.
__global__ __launch_bounds__(256) void k_feat(
    const float4* __restrict__ feat4, const float* __restrict__ mask,
    float4* __restrict__ pcols4, int D4) {
  const int n0 = blockIdx.x * K3R;
  const int t = threadIdx.x;
  float mv = mask[n0 + (t & 63)];
  unsigned long long bits = __ballot(mv != 0.f);   // identical in all 4 waves

  const int c = t & 127;                  // float4 column
  const int p = (t >> 7) << 1;            // 0 or 2: which row pair of each quad
  float4 a0 = {0.f, 0.f, 0.f, 0.f}, a1 = {0.f, 0.f, 0.f, 0.f};
  for (int it = 0; it < K3R; it += 4) {
    int r0 = it + p, r1 = it + p + 1;
    bool b0 = (bits >> r0) & 1;
    bool b1 = (bits >> r1) & 1;
    if (b0) {
      float4 v = feat4[(size_t)(n0 + r0) * D4 + c];
      a0.x += v.x; a0.y += v.y; a0.z += v.z; a0.w += v.w;
    }
    if (b1) {
      float4 v = feat4[(size_t)(n0 + r1) * D4 + c];
      a1.x += v.x; a1.y += v.y; a1.z += v.z; a1.w += v.w;
    }
  }
  a0.x += a1.x; a0.y += a1.y; a0.z += a1.z; a0.w += a1.w;

  __shared__ float4 red[256];
  red[t] = a0;
  __syncthreads();
  if (t < 128) {
    float4 o = red[t + 128];
    a0 = red[t];
    a0.x += o.x; a0.y += o.y; a0.z += o.z; a0.w += o.w;
    pcols4[(size_t)blockIdx.x * D4 + t] = a0;
  }
}

// ---------------- k4a: reduce K3B partial rows -> 64 ----------------
__global__ __launch_bounds__(256) void k_red1(
    const float4* __restrict__ pcols4, float4* __restrict__ pcols2, int D4) {
  const int c = threadIdx.x & 127;
  const int h = threadIdx.x >> 7;
  const int per = K3B / 64;              // 8 partial rows per block
  float4 acc = {0.f, 0.f, 0.f, 0.f};
  for (int r = 0; r < per / 2; ++r) {
    float4 v = pcols4[(size_t)(blockIdx.x * per + h * (per / 2) + r) * D4 + c];
    acc.x += v.x; acc.y += v.y; acc.z += v.z; acc.w += v.w;
  }
  __shared__ float4 red[256];
  red[threadIdx.x] = acc;
  __syncthreads();
  if (threadIdx.x < 128) {
    float4 o = red[threadIdx.x + 128];
    acc = red[threadIdx.x];
    acc.x += o.x; acc.y += o.y; acc.z += o.z; acc.w += o.w;
    pcols2[(size_t)blockIdx.x * D4 + threadIdx.x] = acc;
  }
}

// ---------------- k4b: feat_loss reduce + scalar outputs ----------------
__global__ __launch_bounds__(512) void k_final(
    const float* __restrict__ pcols2, const int* __restrict__ counter,
    float* __restrict__ out, int N, int D) {
  float acc = 0.f;
  for (int dd = threadIdx.x; dd < D; dd += blockDim.x) {
    float s = 0.f;
    for (int c = 0; c < 64; ++c) s += pcols2[c * D + dd];
    acc += fabsf(s);
  }
  __shared__ float red[8];
  for (int off = 32; off > 0; off >>= 1) acc += __shfl_down(acc, off, 64);
  int wid = threadIdx.x >> 6;
  if ((threadIdx.x & 63) == 0) red[wid] = acc;
  __syncthreads();
  if (threadIdx.x == 0) {
    float t = 0.f;
    int nw = blockDim.x >> 6;
    for (int w = 0; w < nw; ++w) t += red[w];
    out[N] = (float)(*counter);          // n_matched
    out[N + 1] = (float)N;               // num_rois
    out[(size_t)5 * N + 2] = t;          // feat_loss
  }
}

extern "C" void kernel_launch(void* const* d_in, const int* in_sizes, int n_in,
                              void* d_out, int out_size, void* d_ws, size_t ws_size,
                              hipStream_t stream) {
  const float* rois = (const float*)d_in[0];
  const float* bbox = (const float*)d_in[1];
  const float* gt   = (const float*)d_in[2];
  const float* feat = (const float*)d_in[3];
  const int N = in_sizes[0] / 4;   // 32768
  const int M = in_sizes[2] / 4;   // 4096
  const int D = in_sizes[3] / N;   // 512
  float* out = (float*)d_out;

  char* ws = (char*)d_ws;
  unsigned long long* partials = (unsigned long long*)ws;
  size_t off = (size_t)CHUNKS * N * sizeof(unsigned long long);
  float* mask = (float*)(ws + off);   off += (size_t)N * sizeof(float);
  float* pcols = (float*)(ws + off);  off += (size_t)K3B * D * sizeof(float);
  float* pcols2 = (float*)(ws + off); off += (size_t)64 * D * sizeof(float);
  int* counter = (int*)(ws + off);

  hipMemsetAsync(counter, 0, sizeof(int), stream);

  dim3 g1(N / 256, CHUNKS);
  k_pairwise<<<g1, 256, 0, stream>>>(rois, gt, partials, N, M);
  k_finalize<<<N / 256, 256, 0, stream>>>(rois, bbox, gt, partials, mask, counter,
                                          out, out + N + 2, N);
  k_feat<<<K3B, 256, 0, stream>>>((const float4*)feat, mask, (float4*)pcols, D / 4);
  k_red1<<<64, 256, 0, stream>>>((const float4*)pcols, (float4*)pcols2, D / 4);
  k_final<<<1, 512, 0, stream>>>(pcols2, counter, out, N, D);
}